// Round 1
// baseline (475.873 us; speedup 1.0000x reference)
//
#include <hip/hip_runtime.h>
#include <stdint.h>

typedef __attribute__((ext_vector_type(8))) short bf16x8;
typedef __attribute__((ext_vector_type(4))) float f32x4;

__device__ __forceinline__ unsigned short f2bf(float f) {
  union { float f; unsigned int u; } c; c.f = f;
  unsigned int u = c.u;
  unsigned int r = u + 0x7FFFu + ((u >> 16) & 1u);   // round-to-nearest-even
  return (unsigned short)(r >> 16);
}

// ---------------- x (f32) -> bf16, 8 elems/thread ----------------
__global__ __launch_bounds__(256) void cvt_x_kernel(const float* __restrict__ x,
                                                    unsigned short* __restrict__ xb) {
  int i = blockIdx.x * 256 + threadIdx.x;          // exact grid, sizes divide
  const float4* p = (const float4*)x + (size_t)i * 2;
  float4 a = p[0], b = p[1];
  unsigned short t[8] = { f2bf(a.x), f2bf(a.y), f2bf(a.z), f2bf(a.w),
                          f2bf(b.x), f2bf(b.y), f2bf(b.z), f2bf(b.w) };
  int4 pk; __builtin_memcpy(&pk, t, 16);
  ((int4*)xb)[i] = pk;
}

// -------- W_eff = weight + 2 * lora_B @ lora_A  -> bf16, 8 elems/thread --------
__global__ __launch_bounds__(256) void weff_kernel(const float* __restrict__ w,
                                                   const float* __restrict__ lA,
                                                   const float* __restrict__ lB,
                                                   unsigned short* __restrict__ wb) {
  const int K = 4096;
  int idx = blockIdx.x * 256 + threadIdx.x;        // over N*K/8
  int o  = idx >> 9;                               // K/8 = 512 chunks per row
  int i0 = (idx & 511) << 3;

  float bl[16];
#pragma unroll
  for (int r = 0; r < 16; r += 4) {
    float4 v = *(const float4*)(lB + o * 16 + r);
    bl[r] = v.x; bl[r + 1] = v.y; bl[r + 2] = v.z; bl[r + 3] = v.w;
  }

  float acc[8] = {0.f, 0.f, 0.f, 0.f, 0.f, 0.f, 0.f, 0.f};
#pragma unroll
  for (int r = 0; r < 16; ++r) {
    float4 a0 = *(const float4*)(lA + (size_t)r * K + i0);
    float4 a1 = *(const float4*)(lA + (size_t)r * K + i0 + 4);
    acc[0] += bl[r] * a0.x; acc[1] += bl[r] * a0.y;
    acc[2] += bl[r] * a0.z; acc[3] += bl[r] * a0.w;
    acc[4] += bl[r] * a1.x; acc[5] += bl[r] * a1.y;
    acc[6] += bl[r] * a1.z; acc[7] += bl[r] * a1.w;
  }

  float4 w0 = *(const float4*)(w + (size_t)o * K + i0);
  float4 w1 = *(const float4*)(w + (size_t)o * K + i0 + 4);
  unsigned short t[8] = {
    f2bf(w0.x + 2.0f * acc[0]), f2bf(w0.y + 2.0f * acc[1]),
    f2bf(w0.z + 2.0f * acc[2]), f2bf(w0.w + 2.0f * acc[3]),
    f2bf(w1.x + 2.0f * acc[4]), f2bf(w1.y + 2.0f * acc[5]),
    f2bf(w1.z + 2.0f * acc[6]), f2bf(w1.w + 2.0f * acc[7]) };
  int4 pk; __builtin_memcpy(&pk, t, 16);
  ((int4*)wb)[idx] = pk;
}

// ---------------- bf16 GEMM: C[M][N] = A[M][K] * B[N][K]^T (m97 structure) ----------------
#define BM 128
#define BN 128
#define BK 32

__device__ __forceinline__ void gload16(const unsigned short* g, unsigned short* l) {
  // async global->LDS, 16B per lane; LDS dest = wave-uniform base + lane*16
  __builtin_amdgcn_global_load_lds((__attribute__((address_space(1))) void*)g,
                                   (__attribute__((address_space(3))) void*)l,
                                   16, 0, 0);
}

__global__ __launch_bounds__(256) void gemm_bt_kernel(const unsigned short* __restrict__ A,
                                                      const unsigned short* __restrict__ B,
                                                      float* __restrict__ C) {
  const int N = 4096, K = 4096;

  __shared__ alignas(16) unsigned short As[BM * BK];   // row-major [128][32]
  __shared__ alignas(16) unsigned short Bs[BN * BK];   // row-major [128][32]

  const int t    = threadIdx.x;
  const int lane = t & 63;
  const int w    = t >> 6;        // wave 0..3
  const int wm   = w >> 1;        // 2x2 wave grid, each wave owns 64x64
  const int wn   = w & 1;

  const int bm0 = blockIdx.y * BM;
  const int bn0 = blockIdx.x * BN;

  // staging: flat 16B chunk f = t (+256 for issue 1); row = f/4, col = (f&3)*8
  const int r0 = t >> 2;
  const int c0 = (t & 3) << 3;

  const unsigned short* gA0 = A + (size_t)(bm0 + r0) * K + c0;
  const unsigned short* gA1 = A + (size_t)(bm0 + r0 + 64) * K + c0;
  const unsigned short* gB0 = B + (size_t)(bn0 + r0) * K + c0;
  const unsigned short* gB1 = B + (size_t)(bn0 + r0 + 64) * K + c0;

  unsigned short* lA0 = As + w * 512;          // (w*64 + 0)  *8 elems
  unsigned short* lA1 = As + 2048 + w * 512;   // (w*64 + 256)*8 elems
  unsigned short* lB0 = Bs + w * 512;
  unsigned short* lB1 = Bs + 2048 + w * 512;

  // MFMA fragment coords (16x16x32): A: row=lane&15, k=8*(lane>>4)+j ; B: col=lane&15, same k
  const int fr = lane & 15;
  const int fk = (lane >> 4) << 3;

  f32x4 acc[4][4] = {};

  for (int kt = 0; kt < K / BK; ++kt) {
    const int ko = kt * BK;
    gload16(gA0 + ko, lA0);
    gload16(gA1 + ko, lA1);
    gload16(gB0 + ko, lB0);
    gload16(gB1 + ko, lB1);
    __syncthreads();   // compiler drains vmcnt(0) before s_barrier -> LDS writes landed

    bf16x8 av[4], bv[4];
#pragma unroll
    for (int mi = 0; mi < 4; ++mi)
      av[mi] = *(const bf16x8*)(As + (wm * 64 + mi * 16 + fr) * BK + fk);
#pragma unroll
    for (int ni = 0; ni < 4; ++ni)
      bv[ni] = *(const bf16x8*)(Bs + (wn * 64 + ni * 16 + fr) * BK + fk);

#pragma unroll
    for (int mi = 0; mi < 4; ++mi)
#pragma unroll
      for (int ni = 0; ni < 4; ++ni)
        acc[mi][ni] = __builtin_amdgcn_mfma_f32_16x16x32_bf16(av[mi], bv[ni], acc[mi][ni], 0, 0, 0);

    __syncthreads();   // all waves done reading before next stage overwrites
  }

  // epilogue: C/D layout col=lane&15, row=4*(lane>>4)+reg
  const int orow = (lane >> 4) << 2;
#pragma unroll
  for (int mi = 0; mi < 4; ++mi) {
#pragma unroll
    for (int ni = 0; ni < 4; ++ni) {
      float* cp = C + (size_t)(bm0 + wm * 64 + mi * 16 + orow) * N
                    + (bn0 + wn * 64 + ni * 16 + fr);
#pragma unroll
      for (int r = 0; r < 4; ++r)
        cp[(size_t)r * N] = acc[mi][ni][r];
    }
  }
}

extern "C" void kernel_launch(void* const* d_in, const int* in_sizes, int n_in,
                              void* d_out, int out_size, void* d_ws, size_t ws_size,
                              hipStream_t stream) {
  const float* x  = (const float*)d_in[0];   // [4,2048,4096] f32
  const float* w  = (const float*)d_in[1];   // [4096,4096]   f32
  const float* lA = (const float*)d_in[2];   // [16,4096]     f32
  const float* lB = (const float*)d_in[3];   // [4096,16]     f32
  float* out = (float*)d_out;                // [4,2048,4096] f32

  const int M = 8192, N = 4096, K = 4096;

  // workspace layout: xb (M*K bf16 = 64MB) | wb (N*K bf16 = 32MB)
  unsigned short* xb = (unsigned short*)d_ws;
  unsigned short* wb = xb + (size_t)M * K;

  cvt_x_kernel<<<dim3((M * K / 8) / 256), dim3(256), 0, stream>>>(x, xb);
  weff_kernel<<<dim3((N * K / 8) / 256), dim3(256), 0, stream>>>(w, lA, lB, wb);
  gemm_bt_kernel<<<dim3(N / BN, M / BM), dim3(256), 0, stream>>>(xb, wb, out);
}

// Round 2
// 329.229 us; speedup vs baseline: 1.4454x; 1.4454x over previous
//
#include <hip/hip_runtime.h>
#include <stdint.h>

typedef __attribute__((ext_vector_type(8))) short bf16x8;
typedef __attribute__((ext_vector_type(4))) float f32x4;

#define GM 8192
#define GN 4096
#define GK 4096
#define KTILES (GK / 64)

__device__ __forceinline__ unsigned short f2bf(float f) {
  union { float f; unsigned int u; } c; c.f = f;
  unsigned int u = c.u;
  unsigned int r = u + 0x7FFFu + ((u >> 16) & 1u);   // round-to-nearest-even
  return (unsigned short)(r >> 16);
}

// ---------------- x (f32) -> bf16, 8 elems/thread ----------------
__global__ __launch_bounds__(256) void cvt_x_kernel(const float* __restrict__ x,
                                                    unsigned short* __restrict__ xb) {
  int i = blockIdx.x * 256 + threadIdx.x;
  const float4* p = (const float4*)x + (size_t)i * 2;
  float4 a = p[0], b = p[1];
  unsigned short t[8] = { f2bf(a.x), f2bf(a.y), f2bf(a.z), f2bf(a.w),
                          f2bf(b.x), f2bf(b.y), f2bf(b.z), f2bf(b.w) };
  int4 pk; __builtin_memcpy(&pk, t, 16);
  ((int4*)xb)[i] = pk;
}

// -------- W_eff = weight + 2 * lora_B @ lora_A -> bf16, 8 elems/thread --------
__global__ __launch_bounds__(256) void weff_kernel(const float* __restrict__ w,
                                                   const float* __restrict__ lA,
                                                   const float* __restrict__ lB,
                                                   unsigned short* __restrict__ wb) {
  const int K = GK;
  int idx = blockIdx.x * 256 + threadIdx.x;
  int o  = idx >> 9;
  int i0 = (idx & 511) << 3;

  float bl[16];
#pragma unroll
  for (int r = 0; r < 16; r += 4) {
    float4 v = *(const float4*)(lB + o * 16 + r);
    bl[r] = v.x; bl[r + 1] = v.y; bl[r + 2] = v.z; bl[r + 3] = v.w;
  }

  float acc[8] = {0.f, 0.f, 0.f, 0.f, 0.f, 0.f, 0.f, 0.f};
#pragma unroll
  for (int r = 0; r < 16; ++r) {
    float4 a0 = *(const float4*)(lA + (size_t)r * K + i0);
    float4 a1 = *(const float4*)(lA + (size_t)r * K + i0 + 4);
    acc[0] += bl[r] * a0.x; acc[1] += bl[r] * a0.y;
    acc[2] += bl[r] * a0.z; acc[3] += bl[r] * a0.w;
    acc[4] += bl[r] * a1.x; acc[5] += bl[r] * a1.y;
    acc[6] += bl[r] * a1.z; acc[7] += bl[r] * a1.w;
  }

  float4 w0 = *(const float4*)(w + (size_t)o * K + i0);
  float4 w1 = *(const float4*)(w + (size_t)o * K + i0 + 4);
  unsigned short t[8] = {
    f2bf(w0.x + 2.0f * acc[0]), f2bf(w0.y + 2.0f * acc[1]),
    f2bf(w0.z + 2.0f * acc[2]), f2bf(w0.w + 2.0f * acc[3]),
    f2bf(w1.x + 2.0f * acc[4]), f2bf(w1.y + 2.0f * acc[5]),
    f2bf(w1.z + 2.0f * acc[6]), f2bf(w1.w + 2.0f * acc[7]) };
  int4 pk; __builtin_memcpy(&pk, t, 16);
  ((int4*)wb)[idx] = pk;
}

// =================== 256x256 8-phase bf16 GEMM: C = A * B^T ===================
// A: [M][K] bf16, B: [N][K] bf16 (W_eff), C: [M][N] f32
// 8 waves (2M x 4N), each wave owns 128x64 of C. BK=64. LDS 128KB dbuf.
// LDS layout per buffer (64KB): A area 32 subtiles (16x32 bf16 = 1KB each,
// index (sr*2+sc)), then B area same. st_16x32 swizzle via pre-swizzled
// global source + swizzled ds_read offset (involution b ^= ((b>>9)&1)<<5).

__device__ __forceinline__ void gload16(const unsigned short* g, char* l) {
  __builtin_amdgcn_global_load_lds((__attribute__((address_space(1))) void*)g,
                                   (__attribute__((address_space(3))) void*)l, 16, 0, 0);
}

__device__ __forceinline__ void barrier_fence() {
  __builtin_amdgcn_sched_barrier(0);
  asm volatile("" ::: "memory");
  __builtin_amdgcn_s_barrier();
  asm volatile("" ::: "memory");
  __builtin_amdgcn_sched_barrier(0);
}

#define MFMA_BF16(a, b, c) __builtin_amdgcn_mfma_f32_16x16x32_bf16((a), (b), (c), 0, 0, 0)

// HALF 0: A subtiles sr in {0..3, 8..11}  (read by all waves' P0 as avLo)
// HALF 1: B subtiles sr in {0,1,4,5,8,9,12,13} (bv0: ni 0-1 for every wn)
// HALF 2: B subtiles sr in {2,3,6,7,10,11,14,15} (bv1)
// HALF 3: A subtiles sr in {4..7, 12..15} (avHi)
template <int HALF>
__device__ __forceinline__ void stage_half(const unsigned short* A, const unsigned short* B,
                                           char* smem, int bm0, int bn0, int w, int lane,
                                           int kt, int buf) {
  int sr, isB;
  if constexpr (HALF == 0)      { sr = w + (w & 4);                 isB = 0; }
  else if constexpr (HALF == 1) { sr = ((w >> 1) << 2) + (w & 1);   isB = 1; }
  else if constexpr (HALF == 2) { sr = ((w >> 1) << 2) + (w & 1) + 2; isB = 1; }
  else                          { sr = w + (w & 4) + 4;             isB = 0; }
  const unsigned short* mat = isB ? B : A;
  const int grow = (isB ? bn0 : bm0) + sr * 16 + (lane >> 2);
  const int gcol = ((lane & 3) * 8) ^ ((lane & 32) ? 16 : 0);   // pre-swizzled source col
#pragma unroll
  for (int sc = 0; sc < 2; ++sc) {
    const unsigned short* src = mat + (size_t)grow * GK + kt * 64 + sc * 32 + gcol;
    char* dst = smem + (buf << 16) + (isB ? 32768 : 0) + ((sr * 2 + sc) << 10);
    gload16(src, dst);
  }
}

__device__ __forceinline__ bf16x8 ldsA(const char* smem, int buf, int sr, int sc, int foff) {
  return *(const bf16x8*)(smem + (buf << 16) + ((sr * 2 + sc) << 10) + foff);
}
__device__ __forceinline__ bf16x8 ldsB(const char* smem, int buf, int sr, int sc, int foff) {
  return *(const bf16x8*)(smem + (buf << 16) + 32768 + ((sr * 2 + sc) << 10) + foff);
}

__global__ __launch_bounds__(512, 2) void gemm_bt_kernel(const unsigned short* __restrict__ A,
                                                         const unsigned short* __restrict__ B,
                                                         float* __restrict__ C) {
  __shared__ alignas(16) char smem[131072];

  const int t = threadIdx.x, lane = t & 63, w = t >> 6;
  const int wm = w >> 2, wn = w & 3;     // 2 x 4 wave grid

  // bijective XCD-chunked swizzle: 512 blocks, 512 % 8 == 0
  const int bid = blockIdx.x;
  const int wg  = (bid & 7) * (512 / 8) + (bid >> 3);
  const int bx = wg & 15, by = wg >> 4;
  const int bm0 = by * 256, bn0 = bx * 256;

  // per-lane swizzled fragment byte offset within a 1KB subtile
  int foff = (lane & 15) * 64 + ((lane >> 4) << 4);
  foff ^= ((foff >> 9) & 1) << 5;

  // prologue: stage K-tile 0 into buf 0
  stage_half<0>(A, B, smem, bm0, bn0, w, lane, 0, 0);
  stage_half<1>(A, B, smem, bm0, bn0, w, lane, 0, 0);
  stage_half<2>(A, B, smem, bm0, bn0, w, lane, 0, 0);
  stage_half<3>(A, B, smem, bm0, bn0, w, lane, 0, 0);
  asm volatile("s_waitcnt vmcnt(0)" ::: "memory");
  barrier_fence();

  f32x4 acc[8][4] = {};
  bf16x8 av[4][2], bv0[2][2], bv1[2][2];

  for (int kt = 0; kt < KTILES; ++kt) {
    const int cur = kt & 1, nxt = cur ^ 1;
    const bool last = (kt == KTILES - 1);

    // ---------------- Phase 0: Q(avLo, bv0) ----------------
#pragma unroll
    for (int mi = 0; mi < 4; ++mi) {
      av[mi][0] = ldsA(smem, cur, wm * 8 + mi, 0, foff);
      av[mi][1] = ldsA(smem, cur, wm * 8 + mi, 1, foff);
    }
#pragma unroll
    for (int ni = 0; ni < 2; ++ni) {
      bv0[ni][0] = ldsB(smem, cur, wn * 4 + ni, 0, foff);
      bv0[ni][1] = ldsB(smem, cur, wn * 4 + ni, 1, foff);
    }
    if (!last) {
      stage_half<0>(A, B, smem, bm0, bn0, w, lane, kt + 1, nxt);
      asm volatile("s_waitcnt vmcnt(4)" ::: "memory");   // hB1(kt) landed
    } else {
      asm volatile("s_waitcnt vmcnt(2)" ::: "memory");   // epilogue drain
    }
    barrier_fence();
    __builtin_amdgcn_s_setprio(1);
#pragma unroll
    for (int mi = 0; mi < 4; ++mi)
#pragma unroll
      for (int ni = 0; ni < 2; ++ni) {
        acc[mi][ni] = MFMA_BF16(av[mi][0], bv0[ni][0], acc[mi][ni]);
        acc[mi][ni] = MFMA_BF16(av[mi][1], bv0[ni][1], acc[mi][ni]);
      }
    __builtin_amdgcn_s_setprio(0);
    barrier_fence();

    // ---------------- Phase 1: Q(avLo, bv1) ----------------
#pragma unroll
    for (int ni = 0; ni < 2; ++ni) {
      bv1[ni][0] = ldsB(smem, cur, wn * 4 + 2 + ni, 0, foff);
      bv1[ni][1] = ldsB(smem, cur, wn * 4 + 2 + ni, 1, foff);
    }
    if (!last) {
      stage_half<1>(A, B, smem, bm0, bn0, w, lane, kt + 1, nxt);
      asm volatile("s_waitcnt vmcnt(4)" ::: "memory");   // hA1(kt) landed
    } else {
      asm volatile("s_waitcnt vmcnt(0)" ::: "memory");
    }
    barrier_fence();
    __builtin_amdgcn_s_setprio(1);
#pragma unroll
    for (int mi = 0; mi < 4; ++mi)
#pragma unroll
      for (int ni = 0; ni < 2; ++ni) {
        acc[mi][2 + ni] = MFMA_BF16(av[mi][0], bv1[ni][0], acc[mi][2 + ni]);
        acc[mi][2 + ni] = MFMA_BF16(av[mi][1], bv1[ni][1], acc[mi][2 + ni]);
      }
    __builtin_amdgcn_s_setprio(0);
    barrier_fence();

    // ---------------- Phase 2: Q(avHi, bv1) ----------------
#pragma unroll
    for (int mi = 0; mi < 4; ++mi) {
      av[mi][0] = ldsA(smem, cur, wm * 8 + 4 + mi, 0, foff);
      av[mi][1] = ldsA(smem, cur, wm * 8 + 4 + mi, 1, foff);
    }
    if (!last) stage_half<2>(A, B, smem, bm0, bn0, w, lane, kt + 1, nxt);
    // no vmcnt here: phase 3 issues no ds_reads
    barrier_fence();
    __builtin_amdgcn_s_setprio(1);
#pragma unroll
    for (int mi = 0; mi < 4; ++mi)
#pragma unroll
      for (int ni = 0; ni < 2; ++ni) {
        acc[4 + mi][2 + ni] = MFMA_BF16(av[mi][0], bv1[ni][0], acc[4 + mi][2 + ni]);
        acc[4 + mi][2 + ni] = MFMA_BF16(av[mi][1], bv1[ni][1], acc[4 + mi][2 + ni]);
      }
    __builtin_amdgcn_s_setprio(0);
    barrier_fence();

    // ---------------- Phase 3: Q(avHi, bv0) ----------------
    if (!last) {
      stage_half<3>(A, B, smem, bm0, bn0, w, lane, kt + 1, nxt);
      asm volatile("s_waitcnt vmcnt(4)" ::: "memory");   // hA0(kt+1), hB0(kt+1) landed
    }
    barrier_fence();
    __builtin_amdgcn_s_setprio(1);
#pragma unroll
    for (int mi = 0; mi < 4; ++mi)
#pragma unroll
      for (int ni = 0; ni < 2; ++ni) {
        acc[4 + mi][ni] = MFMA_BF16(av[mi][0], bv0[ni][0], acc[4 + mi][ni]);
        acc[4 + mi][ni] = MFMA_BF16(av[mi][1], bv0[ni][1], acc[4 + mi][ni]);
      }
    __builtin_amdgcn_s_setprio(0);
    barrier_fence();
  }

  // epilogue: C/D layout col=lane&15, row=4*(lane>>4)+reg
  const int orow = (lane >> 4) << 2;
#pragma unroll
  for (int mi = 0; mi < 8; ++mi) {
#pragma unroll
    for (int ni = 0; ni < 4; ++ni) {
      float* cp = C + (size_t)(bm0 + wm * 128 + mi * 16 + orow) * GN
                    + (bn0 + wn * 64 + ni * 16 + (lane & 15));
#pragma unroll
      for (int r = 0; r < 4; ++r)
        cp[(size_t)r * GN] = acc[mi][ni][r];
    }
  }
}

extern "C" void kernel_launch(void* const* d_in, const int* in_sizes, int n_in,
                              void* d_out, int out_size, void* d_ws, size_t ws_size,
                              hipStream_t stream) {
  const float* x  = (const float*)d_in[0];   // [4,2048,4096] f32
  const float* w  = (const float*)d_in[1];   // [4096,4096]   f32
  const float* lA = (const float*)d_in[2];   // [16,4096]     f32
  const float* lB = (const float*)d_in[3];   // [4096,16]     f32
  float* out = (float*)d_out;                // [4,2048,4096] f32

  const int M = GM, N = GN, K = GK;

  unsigned short* xb = (unsigned short*)d_ws;          // M*K bf16 = 64MB
  unsigned short* wb = xb + (size_t)M * K;             // N*K bf16 = 32MB

  cvt_x_kernel<<<dim3((M * K / 8) / 256), dim3(256), 0, stream>>>(x, xb);
  weff_kernel<<<dim3((N * K / 8) / 256), dim3(256), 0, stream>>>(w, lA, lB, wb);
  gemm_bt_kernel<<<dim3((M / 256) * (N / 256)), dim3(512), 0, stream>>>(xb, wb, out);
}

// Round 3
// 294.525 us; speedup vs baseline: 1.6157x; 1.1178x over previous
//
#include <hip/hip_runtime.h>
#include <stdint.h>

typedef __attribute__((ext_vector_type(8))) short bf16x8;
typedef __attribute__((ext_vector_type(4))) float f32x4;

#define GM 8192
#define GN 4096
#define GK 4096
#define KTILES (GK / 64)

__device__ __forceinline__ unsigned short f2bf(float f) {
  union { float f; unsigned int u; } c; c.f = f;
  unsigned int u = c.u;
  unsigned int r = u + 0x7FFFu + ((u >> 16) & 1u);   // round-to-nearest-even
  return (unsigned short)(r >> 16);
}

// ---------------- x (f32) -> bf16, 8 elems/thread ----------------
__global__ __launch_bounds__(256) void cvt_x_kernel(const float* __restrict__ x,
                                                    unsigned short* __restrict__ xb) {
  int i = blockIdx.x * 256 + threadIdx.x;
  const float4* p = (const float4*)x + (size_t)i * 2;
  float4 a = p[0], b = p[1];
  unsigned short t[8] = { f2bf(a.x), f2bf(a.y), f2bf(a.z), f2bf(a.w),
                          f2bf(b.x), f2bf(b.y), f2bf(b.z), f2bf(b.w) };
  int4 pk; __builtin_memcpy(&pk, t, 16);
  ((int4*)xb)[i] = pk;
}

// -------- W_eff = weight + 2 * lora_B @ lora_A -> bf16 --------
// 8x8 register tile per thread: lA float4 loads shared across 8 rows,
// lB reads wave-uniform (scalar path), w/store coalesced float4.
__global__ __launch_bounds__(256) void weff_kernel(const float* __restrict__ w,
                                                   const float* __restrict__ lA,
                                                   const float* __restrict__ lB,
                                                   unsigned short* __restrict__ wb) {
  const int K = GK;
  int idx = blockIdx.x * 256 + threadIdx.x;   // over (N/8)*(K/8) = 512*512
  int cg = idx & 511;                          // col-chunk (consecutive per lane)
  int rg = idx >> 9;                           // row-group (wave-uniform)
  int i0 = cg << 3;
  int o0 = rg << 3;

  float acc[8][8];
#pragma unroll
  for (int r = 0; r < 8; ++r)
#pragma unroll
    for (int c = 0; c < 8; ++c) acc[r][c] = 0.f;

#pragma unroll
  for (int r = 0; r < 16; ++r) {
    float4 a0 = *(const float4*)(lA + (size_t)r * K + i0);
    float4 a1 = *(const float4*)(lA + (size_t)r * K + i0 + 4);
    float av[8] = { a0.x, a0.y, a0.z, a0.w, a1.x, a1.y, a1.z, a1.w };
#pragma unroll
    for (int row = 0; row < 8; ++row) {
      float b = lB[(size_t)(o0 + row) * 16 + r];
#pragma unroll
      for (int c = 0; c < 8; ++c) acc[row][c] += b * av[c];
    }
  }

#pragma unroll
  for (int row = 0; row < 8; ++row) {
    float4 w0 = *(const float4*)(w + (size_t)(o0 + row) * K + i0);
    float4 w1 = *(const float4*)(w + (size_t)(o0 + row) * K + i0 + 4);
    unsigned short t[8] = {
      f2bf(w0.x + 2.0f * acc[row][0]), f2bf(w0.y + 2.0f * acc[row][1]),
      f2bf(w0.z + 2.0f * acc[row][2]), f2bf(w0.w + 2.0f * acc[row][3]),
      f2bf(w1.x + 2.0f * acc[row][4]), f2bf(w1.y + 2.0f * acc[row][5]),
      f2bf(w1.z + 2.0f * acc[row][6]), f2bf(w1.w + 2.0f * acc[row][7]) };
    int4 pk; __builtin_memcpy(&pk, t, 16);
    *(int4*)(wb + (size_t)(o0 + row) * K + i0) = pk;
  }
}

// =================== 256x256 8-phase bf16 GEMM: C = A * B^T ===================
// 8 waves (2M x 4N), 128x64 C per wave, BK=64, 128KB LDS dbuf,
// st_16x32 swizzle (pre-swizzled global src + swizzled ds_read, 0 conflicts).
// Prefetch 3 half-tiles ahead; counted vmcnt(6), never 0 in main loop.

__device__ __forceinline__ void gload16(const unsigned short* g, char* l) {
  __builtin_amdgcn_global_load_lds((__attribute__((address_space(1))) void*)g,
                                   (__attribute__((address_space(3))) void*)l, 16, 0, 0);
}

__device__ __forceinline__ void bar() {
  asm volatile("" ::: "memory");
  __builtin_amdgcn_s_barrier();
  asm volatile("" ::: "memory");
}

#define MFMA_BF16(a, b, c) __builtin_amdgcn_mfma_f32_16x16x32_bf16((a), (b), (c), 0, 0, 0)

// HALF 0: A subtiles {0..3, 8..11}   (avLo, read at P0)
// HALF 1: B subtiles {0,1,4,5,8,9,12,13}   (bv0, read at P0)
// HALF 2: B subtiles {2,3,6,7,10,11,14,15} (bv1, read at P1)
// HALF 3: A subtiles {4..7, 12..15}  (avHi, read at P2)
template <int HALF>
__device__ __forceinline__ void stage_half(const unsigned short* A, const unsigned short* B,
                                           char* smem, int bm0, int bn0, int w, int lane,
                                           int kt, int buf) {
  int sr, isB;
  if constexpr (HALF == 0)      { sr = w + (w & 4);                   isB = 0; }
  else if constexpr (HALF == 1) { sr = ((w >> 1) << 2) + (w & 1);     isB = 1; }
  else if constexpr (HALF == 2) { sr = ((w >> 1) << 2) + (w & 1) + 2; isB = 1; }
  else                          { sr = w + (w & 4) + 4;               isB = 0; }
  const unsigned short* mat = isB ? B : A;
  const int grow = (isB ? bn0 : bm0) + sr * 16 + (lane >> 2);
  const int gcol = ((lane & 3) * 8) ^ ((lane & 32) ? 16 : 0);   // pre-swizzled source col
#pragma unroll
  for (int sc = 0; sc < 2; ++sc) {
    const unsigned short* src = mat + (size_t)grow * GK + kt * 64 + sc * 32 + gcol;
    char* dst = smem + (buf << 16) + (isB ? 32768 : 0) + ((sr * 2 + sc) << 10);
    gload16(src, dst);
  }
}

__device__ __forceinline__ bf16x8 ldsA(const char* smem, int buf, int sr, int sc, int foff) {
  return *(const bf16x8*)(smem + (buf << 16) + ((sr * 2 + sc) << 10) + foff);
}
__device__ __forceinline__ bf16x8 ldsB(const char* smem, int buf, int sr, int sc, int foff) {
  return *(const bf16x8*)(smem + (buf << 16) + 32768 + ((sr * 2 + sc) << 10) + foff);
}

__global__ __launch_bounds__(512, 2) void gemm_bt_kernel(const unsigned short* __restrict__ A,
                                                         const unsigned short* __restrict__ B,
                                                         float* __restrict__ C) {
  __shared__ alignas(16) char smem[131072];

  const int t = threadIdx.x, lane = t & 63, w = t >> 6;
  const int wm = w >> 2, wn = w & 3;     // 2 x 4 wave grid

  // bijective XCD-chunked swizzle: 512 blocks, 512 % 8 == 0
  const int bid = blockIdx.x;
  const int wg  = (bid & 7) * (512 / 8) + (bid >> 3);
  const int bx = wg & 15, by = wg >> 4;
  const int bm0 = by * 256, bn0 = bx * 256;

  // per-lane swizzled fragment byte offset within a 1KB subtile
  int foff = (lane & 15) * 64 + ((lane >> 4) << 4);
  foff ^= ((foff >> 9) & 1) << 5;

  // prologue: tile 0 (all 4 halves) + h0 of tile 1  -> 10 loads in flight
  stage_half<0>(A, B, smem, bm0, bn0, w, lane, 0, 0);
  stage_half<1>(A, B, smem, bm0, bn0, w, lane, 0, 0);
  stage_half<2>(A, B, smem, bm0, bn0, w, lane, 0, 0);
  stage_half<3>(A, B, smem, bm0, bn0, w, lane, 0, 0);
  stage_half<0>(A, B, smem, bm0, bn0, w, lane, 1, 1);
  asm volatile("s_waitcnt vmcnt(6)" ::: "memory");   // h0,h1(0) landed
  bar();

  f32x4 acc[8][4] = {};
  bf16x8 av[4][2], bv0[2][2], bv1[2][2];

  for (int kt = 0; kt < KTILES; ++kt) {
    const int cur = kt & 1;
    const bool n1 = (kt + 1 < KTILES);
    const bool n2 = (kt + 2 < KTILES);

    // ---------------- Phase 0: Q(avLo, bv0); stage h1(kt+1) ----------------
#pragma unroll
    for (int mi = 0; mi < 4; ++mi) {
      av[mi][0] = ldsA(smem, cur, wm * 8 + mi, 0, foff);
      av[mi][1] = ldsA(smem, cur, wm * 8 + mi, 1, foff);
    }
#pragma unroll
    for (int ni = 0; ni < 2; ++ni) {
      bv0[ni][0] = ldsB(smem, cur, wn * 4 + ni, 0, foff);
      bv0[ni][1] = ldsB(smem, cur, wn * 4 + ni, 1, foff);
    }
    if (n1) {
      stage_half<1>(A, B, smem, bm0, bn0, w, lane, kt + 1, cur ^ 1);
      asm volatile("s_waitcnt vmcnt(6)" ::: "memory");   // h2(kt) landed
    } else {
      asm volatile("s_waitcnt vmcnt(2)" ::: "memory");
    }
    bar();
    asm volatile("s_waitcnt lgkmcnt(0)" ::: "memory");
    __builtin_amdgcn_s_setprio(1);
#pragma unroll
    for (int mi = 0; mi < 4; ++mi)
#pragma unroll
      for (int ni = 0; ni < 2; ++ni) {
        acc[mi][ni] = MFMA_BF16(av[mi][0], bv0[ni][0], acc[mi][ni]);
        acc[mi][ni] = MFMA_BF16(av[mi][1], bv0[ni][1], acc[mi][ni]);
      }
    __builtin_amdgcn_s_setprio(0);
    bar();

    // ---------------- Phase 1: Q(avLo, bv1); stage h2(kt+1) ----------------
#pragma unroll
    for (int ni = 0; ni < 2; ++ni) {
      bv1[ni][0] = ldsB(smem, cur, wn * 4 + 2 + ni, 0, foff);
      bv1[ni][1] = ldsB(smem, cur, wn * 4 + 2 + ni, 1, foff);
    }
    if (n1) {
      stage_half<2>(A, B, smem, bm0, bn0, w, lane, kt + 1, cur ^ 1);
      asm volatile("s_waitcnt vmcnt(6)" ::: "memory");   // h3(kt) landed
    } else {
      asm volatile("s_waitcnt vmcnt(0)" ::: "memory");
    }
    bar();
    asm volatile("s_waitcnt lgkmcnt(0)" ::: "memory");
    __builtin_amdgcn_s_setprio(1);
#pragma unroll
    for (int mi = 0; mi < 4; ++mi)
#pragma unroll
      for (int ni = 0; ni < 2; ++ni) {
        acc[mi][2 + ni] = MFMA_BF16(av[mi][0], bv1[ni][0], acc[mi][2 + ni]);
        acc[mi][2 + ni] = MFMA_BF16(av[mi][1], bv1[ni][1], acc[mi][2 + ni]);
      }
    __builtin_amdgcn_s_setprio(0);
    bar();

    // ---------------- Phase 2: Q(avHi, bv1); stage h3(kt+1) ----------------
#pragma unroll
    for (int mi = 0; mi < 4; ++mi) {
      av[mi][0] = ldsA(smem, cur, wm * 8 + 4 + mi, 0, foff);
      av[mi][1] = ldsA(smem, cur, wm * 8 + 4 + mi, 1, foff);
    }
    if (n1) stage_half<3>(A, B, smem, bm0, bn0, w, lane, kt + 1, cur ^ 1);
    bar();
    asm volatile("s_waitcnt lgkmcnt(0)" ::: "memory");
    __builtin_amdgcn_s_setprio(1);
#pragma unroll
    for (int mi = 0; mi < 4; ++mi)
#pragma unroll
      for (int ni = 0; ni < 2; ++ni) {
        acc[4 + mi][2 + ni] = MFMA_BF16(av[mi][0], bv1[ni][0], acc[4 + mi][2 + ni]);
        acc[4 + mi][2 + ni] = MFMA_BF16(av[mi][1], bv1[ni][1], acc[4 + mi][2 + ni]);
      }
    __builtin_amdgcn_s_setprio(0);
    bar();

    // ---------------- Phase 3: Q(avHi, bv0); stage h0(kt+2) ----------------
    if (n2) stage_half<0>(A, B, smem, bm0, bn0, w, lane, kt + 2, cur);
    if (n1) {
      if (n2) asm volatile("s_waitcnt vmcnt(6)" ::: "memory");   // h0,h1(kt+1) landed
      else    asm volatile("s_waitcnt vmcnt(4)" ::: "memory");
    }
    bar();
    __builtin_amdgcn_s_setprio(1);
#pragma unroll
    for (int mi = 0; mi < 4; ++mi)
#pragma unroll
      for (int ni = 0; ni < 2; ++ni) {
        acc[4 + mi][ni] = MFMA_BF16(av[mi][0], bv0[ni][0], acc[4 + mi][ni]);
        acc[4 + mi][ni] = MFMA_BF16(av[mi][1], bv0[ni][1], acc[4 + mi][ni]);
      }
    __builtin_amdgcn_s_setprio(0);
    bar();
  }

  // epilogue: C/D layout col=lane&15, row=4*(lane>>4)+reg
  const int orow = (lane >> 4) << 2;
#pragma unroll
  for (int mi = 0; mi < 8; ++mi) {
#pragma unroll
    for (int ni = 0; ni < 4; ++ni) {
      float* cp = C + (size_t)(bm0 + wm * 128 + mi * 16 + orow) * GN
                    + (bn0 + wn * 64 + ni * 16 + (lane & 15));
#pragma unroll
      for (int r = 0; r < 4; ++r)
        cp[(size_t)r * GN] = acc[mi][ni][r];
    }
  }
}

extern "C" void kernel_launch(void* const* d_in, const int* in_sizes, int n_in,
                              void* d_out, int out_size, void* d_ws, size_t ws_size,
                              hipStream_t stream) {
  const float* x  = (const float*)d_in[0];   // [4,2048,4096] f32
  const float* w  = (const float*)d_in[1];   // [4096,4096]   f32
  const float* lA = (const float*)d_in[2];   // [16,4096]     f32
  const float* lB = (const float*)d_in[3];   // [4096,16]     f32
  float* out = (float*)d_out;                // [4,2048,4096] f32

  const int M = GM, N = GN, K = GK;

  unsigned short* xb = (unsigned short*)d_ws;          // M*K bf16 = 64MB
  unsigned short* wb = xb + (size_t)M * K;             // N*K bf16 = 32MB

  cvt_x_kernel<<<dim3((M * K / 8) / 256), dim3(256), 0, stream>>>(x, xb);
  weff_kernel<<<dim3((N / 8) * (K / 8) / 256), dim3(256), 0, stream>>>(w, lA, lB, wb);
  gemm_bt_kernel<<<dim3((M / 256) * (N / 256)), dim3(512), 0, stream>>>(xb, wb, out);
}

// Round 4
// 293.430 us; speedup vs baseline: 1.6218x; 1.0037x over previous
//
#include <hip/hip_runtime.h>
#include <stdint.h>

typedef __attribute__((ext_vector_type(8))) short bf16x8;
typedef __attribute__((ext_vector_type(4))) float f32x4;

#define GM 8192
#define GN 4096
#define GK 4096
#define KTILES (GK / 64)

__device__ __forceinline__ unsigned short f2bf(float f) {
  union { float f; unsigned int u; } c; c.f = f;
  unsigned int u = c.u;
  unsigned int r = u + 0x7FFFu + ((u >> 16) & 1u);   // round-to-nearest-even
  return (unsigned short)(r >> 16);
}

// ---------------- x (f32) -> bf16, 8 elems/thread ----------------
__global__ __launch_bounds__(256) void cvt_x_kernel(const float* __restrict__ x,
                                                    unsigned short* __restrict__ xb) {
  int i = blockIdx.x * 256 + threadIdx.x;
  const float4* p = (const float4*)x + (size_t)i * 2;
  float4 a = p[0], b = p[1];
  unsigned short t[8] = { f2bf(a.x), f2bf(a.y), f2bf(a.z), f2bf(a.w),
                          f2bf(b.x), f2bf(b.y), f2bf(b.z), f2bf(b.w) };
  int4 pk; __builtin_memcpy(&pk, t, 16);
  ((int4*)xb)[i] = pk;
}

// -------- W_eff = weight + 2 * lora_B @ lora_A -> bf16 --------
// 8x8 register tile per thread: lA float4 loads shared across 8 rows,
// lB reads wave-uniform (scalar path), w/store coalesced float4.
__global__ __launch_bounds__(256) void weff_kernel(const float* __restrict__ w,
                                                   const float* __restrict__ lA,
                                                   const float* __restrict__ lB,
                                                   unsigned short* __restrict__ wb) {
  const int K = GK;
  int idx = blockIdx.x * 256 + threadIdx.x;   // over (N/8)*(K/8) = 512*512
  int cg = idx & 511;                          // col-chunk (consecutive per lane)
  int rg = idx >> 9;                           // row-group (wave-uniform)
  int i0 = cg << 3;
  int o0 = rg << 3;

  float acc[8][8];
#pragma unroll
  for (int r = 0; r < 8; ++r)
#pragma unroll
    for (int c = 0; c < 8; ++c) acc[r][c] = 0.f;

#pragma unroll
  for (int r = 0; r < 16; ++r) {
    float4 a0 = *(const float4*)(lA + (size_t)r * K + i0);
    float4 a1 = *(const float4*)(lA + (size_t)r * K + i0 + 4);
    float av[8] = { a0.x, a0.y, a0.z, a0.w, a1.x, a1.y, a1.z, a1.w };
#pragma unroll
    for (int row = 0; row < 8; ++row) {
      float b = lB[(size_t)(o0 + row) * 16 + r];
#pragma unroll
      for (int c = 0; c < 8; ++c) acc[row][c] += b * av[c];
    }
  }

#pragma unroll
  for (int row = 0; row < 8; ++row) {
    float4 w0 = *(const float4*)(w + (size_t)(o0 + row) * K + i0);
    float4 w1 = *(const float4*)(w + (size_t)(o0 + row) * K + i0 + 4);
    unsigned short t[8] = {
      f2bf(w0.x + 2.0f * acc[row][0]), f2bf(w0.y + 2.0f * acc[row][1]),
      f2bf(w0.z + 2.0f * acc[row][2]), f2bf(w0.w + 2.0f * acc[row][3]),
      f2bf(w1.x + 2.0f * acc[row][4]), f2bf(w1.y + 2.0f * acc[row][5]),
      f2bf(w1.z + 2.0f * acc[row][6]), f2bf(w1.w + 2.0f * acc[row][7]) };
    int4 pk; __builtin_memcpy(&pk, t, 16);
    *(int4*)(wb + (size_t)(o0 + row) * K + i0) = pk;
  }
}

// =================== 256x256 8-phase bf16 GEMM: C = A * B^T ===================
// 8 waves (2M x 4N), 128x64 C per wave, BK=64, 128KB LDS dbuf,
// st_16x32 swizzle (pre-swizzled global src + swizzled ds_read, 0 conflicts).
// Prefetch 3 half-tiles ahead; counted vmcnt(6), never 0 in main loop.

__device__ __forceinline__ void gload16(const unsigned short* g, char* l) {
  __builtin_amdgcn_global_load_lds((__attribute__((address_space(1))) void*)g,
                                   (__attribute__((address_space(3))) void*)l, 16, 0, 0);
}

__device__ __forceinline__ void bar() {
  asm volatile("" ::: "memory");
  __builtin_amdgcn_s_barrier();
  asm volatile("" ::: "memory");
}

#define MFMA_BF16(a, b, c) __builtin_amdgcn_mfma_f32_16x16x32_bf16((a), (b), (c), 0, 0, 0)

// HALF 0: A subtiles {0..3, 8..11}   (avLo, read at P0)
// HALF 1: B subtiles {0,1,4,5,8,9,12,13}   (bv0, read at P0)
// HALF 2: B subtiles {2,3,6,7,10,11,14,15} (bv1, read at P1)
// HALF 3: A subtiles {4..7, 12..15}  (avHi, read at P2)
template <int HALF>
__device__ __forceinline__ void stage_half(const unsigned short* A, const unsigned short* B,
                                           char* smem, int bm0, int bn0, int w, int lane,
                                           int kt, int buf) {
  int sr, isB;
  if constexpr (HALF == 0)      { sr = w + (w & 4);                   isB = 0; }
  else if constexpr (HALF == 1) { sr = ((w >> 1) << 2) + (w & 1);     isB = 1; }
  else if constexpr (HALF == 2) { sr = ((w >> 1) << 2) + (w & 1) + 2; isB = 1; }
  else                          { sr = w + (w & 4) + 4;               isB = 0; }
  const unsigned short* mat = isB ? B : A;
  const int grow = (isB ? bn0 : bm0) + sr * 16 + (lane >> 2);
  const int gcol = ((lane & 3) * 8) ^ ((lane & 32) ? 16 : 0);   // pre-swizzled source col
#pragma unroll
  for (int sc = 0; sc < 2; ++sc) {
    const unsigned short* src = mat + (size_t)grow * GK + kt * 64 + sc * 32 + gcol;
    char* dst = smem + (buf << 16) + (isB ? 32768 : 0) + ((sr * 2 + sc) << 10);
    gload16(src, dst);
  }
}

__device__ __forceinline__ bf16x8 ldsA(const char* smem, int buf, int sr, int sc, int foff) {
  return *(const bf16x8*)(smem + (buf << 16) + ((sr * 2 + sc) << 10) + foff);
}
__device__ __forceinline__ bf16x8 ldsB(const char* smem, int buf, int sr, int sc, int foff) {
  return *(const bf16x8*)(smem + (buf << 16) + 32768 + ((sr * 2 + sc) << 10) + foff);
}

__global__ __launch_bounds__(512, 2) void gemm_bt_kernel(const unsigned short* __restrict__ A,
                                                         const unsigned short* __restrict__ B,
                                                         float* __restrict__ C) {
  __shared__ alignas(16) char smem[131072];

  const int t = threadIdx.x, lane = t & 63, w = t >> 6;
  const int wm = w >> 2, wn = w & 3;     // 2 x 4 wave grid

  // bijective XCD-chunked swizzle: 512 blocks, 512 % 8 == 0
  const int bid = blockIdx.x;
  const int wg  = (bid & 7) * (512 / 8) + (bid >> 3);
  const int bx = wg & 15, by = wg >> 4;
  const int bm0 = by * 256, bn0 = bx * 256;

  // per-lane swizzled fragment byte offset within a 1KB subtile
  int foff = (lane & 15) * 64 + ((lane >> 4) << 4);
  foff ^= ((foff >> 9) & 1) << 5;

  // prologue: tile 0 (all 4 halves) + h0 of tile 1  -> 10 loads in flight
  stage_half<0>(A, B, smem, bm0, bn0, w, lane, 0, 0);
  stage_half<1>(A, B, smem, bm0, bn0, w, lane, 0, 0);
  stage_half<2>(A, B, smem, bm0, bn0, w, lane, 0, 0);
  stage_half<3>(A, B, smem, bm0, bn0, w, lane, 0, 0);
  stage_half<0>(A, B, smem, bm0, bn0, w, lane, 1, 1);
  asm volatile("s_waitcnt vmcnt(6)" ::: "memory");   // h0,h1(0) landed
  bar();

  f32x4 acc[8][4] = {};
  bf16x8 av[4][2], bv0[2][2], bv1[2][2];

  for (int kt = 0; kt < KTILES; ++kt) {
    const int cur = kt & 1;
    const bool n1 = (kt + 1 < KTILES);
    const bool n2 = (kt + 2 < KTILES);

    // ---------------- Phase 0: Q(avLo, bv0); stage h1(kt+1) ----------------
#pragma unroll
    for (int mi = 0; mi < 4; ++mi) {
      av[mi][0] = ldsA(smem, cur, wm * 8 + mi, 0, foff);
      av[mi][1] = ldsA(smem, cur, wm * 8 + mi, 1, foff);
    }
#pragma unroll
    for (int ni = 0; ni < 2; ++ni) {
      bv0[ni][0] = ldsB(smem, cur, wn * 4 + ni, 0, foff);
      bv0[ni][1] = ldsB(smem, cur, wn * 4 + ni, 1, foff);
    }
    if (n1) {
      stage_half<1>(A, B, smem, bm0, bn0, w, lane, kt + 1, cur ^ 1);
      asm volatile("s_waitcnt vmcnt(6)" ::: "memory");   // h2(kt) landed
    } else {
      asm volatile("s_waitcnt vmcnt(2)" ::: "memory");
    }
    bar();
    asm volatile("s_waitcnt lgkmcnt(0)" ::: "memory");
    __builtin_amdgcn_s_setprio(1);
#pragma unroll
    for (int mi = 0; mi < 4; ++mi)
#pragma unroll
      for (int ni = 0; ni < 2; ++ni) {
        acc[mi][ni] = MFMA_BF16(av[mi][0], bv0[ni][0], acc[mi][ni]);
        acc[mi][ni] = MFMA_BF16(av[mi][1], bv0[ni][1], acc[mi][ni]);
      }
    __builtin_amdgcn_s_setprio(0);
    bar();

    // ---------------- Phase 1: Q(avLo, bv1); stage h2(kt+1) ----------------
#pragma unroll
    for (int ni = 0; ni < 2; ++ni) {
      bv1[ni][0] = ldsB(smem, cur, wn * 4 + 2 + ni, 0, foff);
      bv1[ni][1] = ldsB(smem, cur, wn * 4 + 2 + ni, 1, foff);
    }
    if (n1) {
      stage_half<2>(A, B, smem, bm0, bn0, w, lane, kt + 1, cur ^ 1);
      asm volatile("s_waitcnt vmcnt(6)" ::: "memory");   // h3(kt) landed
    } else {
      asm volatile("s_waitcnt vmcnt(0)" ::: "memory");
    }
    bar();
    asm volatile("s_waitcnt lgkmcnt(0)" ::: "memory");
    __builtin_amdgcn_s_setprio(1);
#pragma unroll
    for (int mi = 0; mi < 4; ++mi)
#pragma unroll
      for (int ni = 0; ni < 2; ++ni) {
        acc[mi][2 + ni] = MFMA_BF16(av[mi][0], bv1[ni][0], acc[mi][2 + ni]);
        acc[mi][2 + ni] = MFMA_BF16(av[mi][1], bv1[ni][1], acc[mi][2 + ni]);
      }
    __builtin_amdgcn_s_setprio(0);
    bar();

    // ---------------- Phase 2: Q(avHi, bv1); stage h3(kt+1) ----------------
#pragma unroll
    for (int mi = 0; mi < 4; ++mi) {
      av[mi][0] = ldsA(smem, cur, wm * 8 + 4 + mi, 0, foff);
      av[mi][1] = ldsA(smem, cur, wm * 8 + 4 + mi, 1, foff);
    }
    if (n1) stage_half<3>(A, B, smem, bm0, bn0, w, lane, kt + 1, cur ^ 1);
    bar();
    asm volatile("s_waitcnt lgkmcnt(0)" ::: "memory");
    __builtin_amdgcn_s_setprio(1);
#pragma unroll
    for (int mi = 0; mi < 4; ++mi)
#pragma unroll
      for (int ni = 0; ni < 2; ++ni) {
        acc[4 + mi][2 + ni] = MFMA_BF16(av[mi][0], bv1[ni][0], acc[4 + mi][2 + ni]);
        acc[4 + mi][2 + ni] = MFMA_BF16(av[mi][1], bv1[ni][1], acc[4 + mi][2 + ni]);
      }
    __builtin_amdgcn_s_setprio(0);
    bar();

    // ---------------- Phase 3: Q(avHi, bv0); stage h0(kt+2) ----------------
    if (n2) stage_half<0>(A, B, smem, bm0, bn0, w, lane, kt + 2, cur);
    if (n1) {
      if (n2) asm volatile("s_waitcnt vmcnt(6)" ::: "memory");   // h0,h1(kt+1) landed
      else    asm volatile("s_waitcnt vmcnt(4)" ::: "memory");
    }
    bar();
    __builtin_amdgcn_s_setprio(1);
#pragma unroll
    for (int mi = 0; mi < 4; ++mi)
#pragma unroll
      for (int ni = 0; ni < 2; ++ni) {
        acc[4 + mi][ni] = MFMA_BF16(av[mi][0], bv0[ni][0], acc[4 + mi][ni]);
        acc[4 + mi][ni] = MFMA_BF16(av[mi][1], bv0[ni][1], acc[4 + mi][ni]);
      }
    __builtin_amdgcn_s_setprio(0);
    bar();
  }

  // epilogue: C/D layout col=lane&15, row=4*(lane>>4)+reg
  const int orow = (lane >> 4) << 2;
#pragma unroll
  for (int mi = 0; mi < 8; ++mi) {
#pragma unroll
    for (int ni = 0; ni < 4; ++ni) {
      float* cp = C + (size_t)(bm0 + wm * 128 + mi * 16 + orow) * GN
                    + (bn0 + wn * 64 + ni * 16 + (lane & 15));
#pragma unroll
      for (int r = 0; r < 4; ++r)
        cp[(size_t)r * GN] = acc[mi][ni][r];
    }
  }
}

extern "C" void kernel_launch(void* const* d_in, const int* in_sizes, int n_in,
                              void* d_out, int out_size, void* d_ws, size_t ws_size,
                              hipStream_t stream) {
  const float* x  = (const float*)d_in[0];   // [4,2048,4096] f32
  const float* w  = (const float*)d_in[1];   // [4096,4096]   f32
  const float* lA = (const float*)d_in[2];   // [16,4096]     f32
  const float* lB = (const float*)d_in[3];   // [4096,16]     f32
  float* out = (float*)d_out;                // [4,2048,4096] f32

  const int M = GM, N = GN, K = GK;

  unsigned short* xb = (unsigned short*)d_ws;          // M*K bf16 = 64MB
  unsigned short* wb = xb + (size_t)M * K;             // N*K bf16 = 32MB

  cvt_x_kernel<<<dim3((M * K / 8) / 256), dim3(256), 0, stream>>>(x, xb);
  weff_kernel<<<dim3((N / 8) * (K / 8) / 256), dim3(256), 0, stream>>>(w, lA, lB, wb);
  gemm_bt_kernel<<<dim3((M / 256) * (N / 256)), dim3(512), 0, stream>>>(xb, wb, out);
}